// Round 3
// baseline (284.975 us; speedup 1.0000x reference)
//
#include <hip/hip_runtime.h>
#include <math.h>

// DraftSampler: B=256 rows, V=128000 vocab, fp32.
// Single streaming pass (log-domain Gumbel-max):
//   greedy  = argmax_i l_i
//   sampled = argmax_i [ l_i/t * log2(e) - log2(z_i + 1e-10) ]
// (log2 is strictly monotone => same argmax as exp(l/t - M/t)/(z+eps);
//  no row-max needed => no second pass, no inter-phase sync)
// Row split into SEGS column segments -> 2048 blocks -> full occupancy.

#define SEGS 8

__device__ __forceinline__ void amax_combine(float& v, int& i, float ov, int oi) {
    // larger value wins; exact tie -> smaller index (jnp.argmax first-occurrence)
    if (ov > v || (ov == v && oi < i)) { v = ov; i = oi; }
}

__global__ __launch_bounds__(256) void draft_pass1(
    const float* __restrict__ logits,
    const float* __restrict__ temps,
    const float* __restrict__ noise,
    float4* __restrict__ ws,      // [B*SEGS] = {greedy_v, greedy_i, samp_v, samp_i}
    int V)
{
    const int seg = blockIdx.x;
    const int row = blockIdx.y;
    const int tid = threadIdx.x;
    const int lane = tid & 63;
    const int wid  = tid >> 6;            // 0..3

    const int n4  = V >> 2;               // float4 count per row
    const int per = n4 / SEGS;
    const int j0  = seg * per;
    const int j1  = (seg == SEGS - 1) ? n4 : (j0 + per);

    const float t = temps[row];
    const float safe_t = (t == 0.0f) ? 1.0f : t;
    const float c = (1.0f / safe_t) * 1.4426950408889634f;   // log2(e)/t

    const size_t base = (size_t)row * (size_t)V;
    const float4* l4 = (const float4*)(logits + base);
    const float4* z4 = (const float4*)(noise + base);

    float gv = -INFINITY; int gi = 0x7fffffff;   // greedy partial
    float sv = -INFINITY; int si = 0x7fffffff;   // sampled partial

    for (int j = j0 + tid; j < j1; j += 256) {
        float4 x = l4[j];
        float4 z = z4[j];
        int k = j << 2;
        // greedy argmax of raw logits (ascending k per thread + strict > => first occurrence)
        if (x.x > gv) { gv = x.x; gi = k;     }
        if (x.y > gv) { gv = x.y; gi = k + 1; }
        if (x.z > gv) { gv = x.z; gi = k + 2; }
        if (x.w > gv) { gv = x.w; gi = k + 3; }
        // sampled score in log2 domain: 1 v_log + 1 fma + 1 add per element
        float s0 = fmaf(x.x, c, -__log2f(z.x + 1e-10f));
        float s1 = fmaf(x.y, c, -__log2f(z.y + 1e-10f));
        float s2 = fmaf(x.z, c, -__log2f(z.z + 1e-10f));
        float s3 = fmaf(x.w, c, -__log2f(z.w + 1e-10f));
        if (s0 > sv) { sv = s0; si = k;     }
        if (s1 > sv) { sv = s1; si = k + 1; }
        if (s2 > sv) { sv = s2; si = k + 2; }
        if (s3 > sv) { sv = s3; si = k + 3; }
    }

    // wave (64-lane) reduction for both argmaxes
    #pragma unroll
    for (int off = 32; off > 0; off >>= 1) {
        float ogv = __shfl_down(gv, off, 64);
        int   ogi = __shfl_down(gi, off, 64);
        amax_combine(gv, gi, ogv, ogi);
        float osv = __shfl_down(sv, off, 64);
        int   osi = __shfl_down(si, off, 64);
        amax_combine(sv, si, osv, osi);
    }

    __shared__ float sgv[4]; __shared__ int sgi[4];
    __shared__ float ssv[4]; __shared__ int ssi[4];
    if (lane == 0) { sgv[wid] = gv; sgi[wid] = gi; ssv[wid] = sv; ssi[wid] = si; }
    __syncthreads();
    if (tid == 0) {
        float bgv = sgv[0]; int bgi = sgi[0];
        float bsv = ssv[0]; int bsi = ssi[0];
        #pragma unroll
        for (int w = 1; w < 4; ++w) {
            amax_combine(bgv, bgi, sgv[w], sgi[w]);
            amax_combine(bsv, bsi, ssv[w], ssi[w]);
        }
        float4 p;
        p.x = bgv; p.y = __int_as_float(bgi);
        p.z = bsv; p.w = __int_as_float(bsi);
        ws[(size_t)row * SEGS + seg] = p;
    }
}

__global__ __launch_bounds__(256) void draft_pass2(
    const float* __restrict__ temps,
    const float4* __restrict__ ws,
    int* __restrict__ out,
    int B)
{
    int r = blockIdx.x * blockDim.x + threadIdx.x;
    if (r >= B) return;
    float gv = -INFINITY; int gi = 0x7fffffff;
    float sv = -INFINITY; int si = 0x7fffffff;
    #pragma unroll
    for (int s = 0; s < SEGS; ++s) {
        float4 p = ws[(size_t)r * SEGS + s];
        amax_combine(gv, gi, p.x, __float_as_int(p.y));
        amax_combine(sv, si, p.z, __float_as_int(p.w));
    }
    out[r] = (temps[r] == 0.0f) ? gi : si;
}

extern "C" void kernel_launch(void* const* d_in, const int* in_sizes, int n_in,
                              void* d_out, int out_size, void* d_ws, size_t ws_size,
                              hipStream_t stream) {
    const float* logits = (const float*)d_in[0];
    const float* temps  = (const float*)d_in[1];
    const float* noise  = (const float*)d_in[2];
    int* out = (int*)d_out;

    const int B = in_sizes[1];              // 256
    const int V = in_sizes[0] / B;          // 128000

    float4* ws = (float4*)d_ws;             // B*SEGS*16 bytes = 32 KiB

    dim3 grid1(SEGS, B);
    draft_pass1<<<grid1, 256, 0, stream>>>(logits, temps, noise, ws, V);
    draft_pass2<<<(B + 255) / 256, 256, 0, stream>>>(temps, ws, out, B);
}

// Round 7
// 279.500 us; speedup vs baseline: 1.0196x; 1.0196x over previous
//
#include <hip/hip_runtime.h>
#include <math.h>

// DraftSampler: B=256 rows, V=128000 vocab, fp32.
// Per-row uniform metric (t is block-uniform):
//   t==0 : metric = logits[i]                       (greedy argmax)
//   t!=0 : metric = l_i/t*log2e - log2(z_i + 1e-10) (log-domain Gumbel-max,
//          strictly monotone transform of exp(l/t - M/t)/(z+eps))
// out[row] = argmax_i metric.  Row split into SEGS segments (2048 blocks),
// 8-deep explicit load batching for memory-level parallelism.

#define SEGS 8
#define NTHR 256
#define UNR  8

__device__ __forceinline__ void amax_combine(float& v, int& i, float ov, int oi) {
    // larger value wins; exact tie -> smaller index (jnp.argmax first-occurrence)
    if (ov > v || (ov == v && oi < i)) { v = ov; i = oi; }
}

__device__ __forceinline__ void upd4(float4 x, int k, float& v, int& i) {
    if (x.x > v) { v = x.x; i = k;     }
    if (x.y > v) { v = x.y; i = k + 1; }
    if (x.z > v) { v = x.z; i = k + 2; }
    if (x.w > v) { v = x.w; i = k + 3; }
}

__global__ __launch_bounds__(NTHR) void draft_pass1(
    const float* __restrict__ logits,
    const float* __restrict__ temps,
    const float* __restrict__ noise,
    float2* __restrict__ ws,      // [B*SEGS] = {metric_v, metric_i}
    int V)
{
    const int seg = blockIdx.x;
    const int row = blockIdx.y;
    const int tid = threadIdx.x;
    const int lane = tid & 63;
    const int wid  = tid >> 6;            // 0..3

    const int n4  = V >> 2;
    const int per = n4 / SEGS;
    const int j0  = seg * per;
    const int j1  = (seg == SEGS - 1) ? n4 : (j0 + per);

    const float t = temps[row];           // block-uniform
    const size_t base = (size_t)row * (size_t)V;
    const float4* l4 = (const float4*)(logits + base);

    float av = -INFINITY; int ai = 0x7fffffff;

    if (t == 0.0f) {
        // ---- greedy: argmax of raw logits; noise never read ----
        int j = j0 + tid;
        for (; j + NTHR * (UNR - 1) < j1; j += NTHR * UNR) {
            float4 xs[UNR];
            #pragma unroll
            for (int u = 0; u < UNR; ++u) xs[u] = l4[j + u * NTHR];
            #pragma unroll
            for (int u = 0; u < UNR; ++u) upd4(xs[u], (j + u * NTHR) << 2, av, ai);
        }
        for (; j < j1; j += NTHR) upd4(l4[j], j << 2, av, ai);
    } else {
        // ---- sampled: log-domain Gumbel-max score ----
        const float c = (1.0f / t) * 1.4426950408889634f;   // log2(e)/t
        const float4* z4 = (const float4*)(noise + base);
        int j = j0 + tid;
        for (; j + NTHR * (UNR - 1) < j1; j += NTHR * UNR) {
            float4 xs[UNR], zs[UNR];
            #pragma unroll
            for (int u = 0; u < UNR; ++u) xs[u] = l4[j + u * NTHR];
            #pragma unroll
            for (int u = 0; u < UNR; ++u) zs[u] = z4[j + u * NTHR];
            #pragma unroll
            for (int u = 0; u < UNR; ++u) {
                float4 x = xs[u], z = zs[u];
                int k = (j + u * NTHR) << 2;
                float4 s;
                s.x = fmaf(x.x, c, -__log2f(z.x + 1e-10f));
                s.y = fmaf(x.y, c, -__log2f(z.y + 1e-10f));
                s.z = fmaf(x.z, c, -__log2f(z.z + 1e-10f));
                s.w = fmaf(x.w, c, -__log2f(z.w + 1e-10f));
                upd4(s, k, av, ai);
            }
        }
        for (; j < j1; j += NTHR) {
            float4 x = l4[j]; float4 z = z4[j];
            float4 s;
            s.x = fmaf(x.x, c, -__log2f(z.x + 1e-10f));
            s.y = fmaf(x.y, c, -__log2f(z.y + 1e-10f));
            s.z = fmaf(x.z, c, -__log2f(z.z + 1e-10f));
            s.w = fmaf(x.w, c, -__log2f(z.w + 1e-10f));
            upd4(s, j << 2, av, ai);
        }
    }

    // ---- wave (64-lane) reduction ----
    #pragma unroll
    for (int off = 32; off > 0; off >>= 1) {
        float ov = __shfl_down(av, off, 64);
        int   oi = __shfl_down(ai, off, 64);
        amax_combine(av, ai, ov, oi);
    }
    __shared__ float svv[4]; __shared__ int sii[4];
    if (lane == 0) { svv[wid] = av; sii[wid] = ai; }
    __syncthreads();
    if (tid == 0) {
        float bv = svv[0]; int bi = sii[0];
        #pragma unroll
        for (int w = 1; w < 4; ++w) amax_combine(bv, bi, svv[w], sii[w]);
        ws[(size_t)row * SEGS + seg] = make_float2(bv, __int_as_float(bi));
    }
}

__global__ __launch_bounds__(256) void draft_pass2(
    const float2* __restrict__ ws,
    int* __restrict__ out,
    int B)
{
    int r = blockIdx.x * blockDim.x + threadIdx.x;
    if (r >= B) return;
    float v = -INFINITY; int i = 0x7fffffff;
    #pragma unroll
    for (int s = 0; s < SEGS; ++s) {
        float2 p = ws[(size_t)r * SEGS + s];
        amax_combine(v, i, p.x, __float_as_int(p.y));
    }
    out[r] = i;
}

extern "C" void kernel_launch(void* const* d_in, const int* in_sizes, int n_in,
                              void* d_out, int out_size, void* d_ws, size_t ws_size,
                              hipStream_t stream) {
    const float* logits = (const float*)d_in[0];
    const float* temps  = (const float*)d_in[1];
    const float* noise  = (const float*)d_in[2];
    int* out = (int*)d_out;

    const int B = in_sizes[1];              // 256
    const int V = in_sizes[0] / B;          // 128000

    float2* ws = (float2*)d_ws;             // B*SEGS*8 B = 16 KiB

    dim3 grid1(SEGS, B);
    draft_pass1<<<grid1, NTHR, 0, stream>>>(logits, temps, noise, ws, V);
    draft_pass2<<<(B + 255) / 256, 256, 0, stream>>>(ws, out, B);
}

// Round 10
// 275.219 us; speedup vs baseline: 1.0354x; 1.0156x over previous
//
#include <hip/hip_runtime.h>
#include <math.h>

// DraftSampler: B=256 rows, V=128000 vocab, fp32.
//   t==0 : metric = logits[i]                       (greedy argmax)
//   t!=0 : metric = l_i/t*log2e - log2(z_i + 1e-10) (log-domain Gumbel-max)
// out[row] = argmax_i metric.
// Forced memory-level parallelism: inline-asm global_load_dwordx4 issued
// 20-deep per thread, drained with counted s_waitcnt vmcnt(N).
// Rule #18: waitcnt has "memory" clobber + sched_barrier(0) so the scheduler
// cannot hoist register-only consumers above the wait (tied "+v" on float4
// is unsupported -> this is the sanctioned pattern).

#define SEGS 4
#define NTHR 256
#define UNR  10   // 10 float4-pairs (x,z) in flight = 20 loads = 20KB/wave

#define GLOAD(dst, p) asm volatile("global_load_dwordx4 %0, %1, off" : "=v"(dst) : "v"(p))
#define VMWAIT(imm) do { asm volatile("s_waitcnt vmcnt(" imm ")" ::: "memory"); \
                         __builtin_amdgcn_sched_barrier(0); } while (0)

__device__ __forceinline__ void amax_combine(float& v, int& i, float ov, int oi) {
    if (ov > v || (ov == v && oi < i)) { v = ov; i = oi; }
}

__device__ __forceinline__ void upd4(float4 x, int k, float& v, int& i) {
    if (x.x > v) { v = x.x; i = k;     }
    if (x.y > v) { v = x.y; i = k + 1; }
    if (x.z > v) { v = x.z; i = k + 2; }
    if (x.w > v) { v = x.w; i = k + 3; }
}

__device__ __forceinline__ void score4(float4 x, float4 z, float c, int k, float& v, int& i) {
    float4 s;
    s.x = fmaf(x.x, c, -__log2f(z.x + 1e-10f));
    s.y = fmaf(x.y, c, -__log2f(z.y + 1e-10f));
    s.z = fmaf(x.z, c, -__log2f(z.z + 1e-10f));
    s.w = fmaf(x.w, c, -__log2f(z.w + 1e-10f));
    upd4(s, k, v, i);
}

__global__ __launch_bounds__(NTHR) void draft_pass1(
    const float* __restrict__ logits,
    const float* __restrict__ temps,
    const float* __restrict__ noise,
    float2* __restrict__ ws,      // [B*SEGS] = {metric_v, metric_i}
    int V)
{
    const int seg = blockIdx.x;
    const int row = blockIdx.y;
    const int tid = threadIdx.x;
    const int lane = tid & 63;
    const int wid  = tid >> 6;

    const int n4  = V >> 2;               // 32000
    const int per = n4 / SEGS;            // 8000
    const int j0  = seg * per;
    const int j1  = (seg == SEGS - 1) ? n4 : (j0 + per);

    const float t = temps[row];           // block-uniform
    const size_t base = (size_t)row * (size_t)V;
    const float4* l4 = (const float4*)(logits + base);

    float av = -INFINITY; int ai = 0x7fffffff;

    if (t == 0.0f) {
        // ---- greedy: 10 forced in-flight loads of logits ----
        int j = j0 + tid;
        for (; j + NTHR * (UNR - 1) < j1; j += NTHR * UNR) {
            float4 x0,x1,x2,x3,x4,x5,x6,x7,x8,x9;
            GLOAD(x0, l4 + j);
            GLOAD(x1, l4 + j + 1*NTHR);
            GLOAD(x2, l4 + j + 2*NTHR);
            GLOAD(x3, l4 + j + 3*NTHR);
            GLOAD(x4, l4 + j + 4*NTHR);
            GLOAD(x5, l4 + j + 5*NTHR);
            GLOAD(x6, l4 + j + 6*NTHR);
            GLOAD(x7, l4 + j + 7*NTHR);
            GLOAD(x8, l4 + j + 8*NTHR);
            GLOAD(x9, l4 + j + 9*NTHR);
            VMWAIT("9"); upd4(x0, (j          ) << 2, av, ai);
            VMWAIT("8"); upd4(x1, (j + 1*NTHR) << 2, av, ai);
            VMWAIT("7"); upd4(x2, (j + 2*NTHR) << 2, av, ai);
            VMWAIT("6"); upd4(x3, (j + 3*NTHR) << 2, av, ai);
            VMWAIT("5"); upd4(x4, (j + 4*NTHR) << 2, av, ai);
            VMWAIT("4"); upd4(x5, (j + 5*NTHR) << 2, av, ai);
            VMWAIT("3"); upd4(x6, (j + 6*NTHR) << 2, av, ai);
            VMWAIT("2"); upd4(x7, (j + 7*NTHR) << 2, av, ai);
            VMWAIT("1"); upd4(x8, (j + 8*NTHR) << 2, av, ai);
            VMWAIT("0"); upd4(x9, (j + 9*NTHR) << 2, av, ai);
        }
        for (; j < j1; j += NTHR) upd4(l4[j], j << 2, av, ai);
    } else {
        // ---- sampled: 10 pairs (x,z) = 20 forced in-flight loads ----
        const float c = (1.0f / t) * 1.4426950408889634f;   // log2(e)/t
        const float4* z4 = (const float4*)(noise + base);
        int j = j0 + tid;
        for (; j + NTHR * (UNR - 1) < j1; j += NTHR * UNR) {
            float4 x0,x1,x2,x3,x4,x5,x6,x7,x8,x9;
            float4 z0,z1,z2,z3,z4_,z5,z6,z7,z8,z9;
            GLOAD(x0, l4 + j);            GLOAD(z0, z4 + j);
            GLOAD(x1, l4 + j + 1*NTHR);   GLOAD(z1, z4 + j + 1*NTHR);
            GLOAD(x2, l4 + j + 2*NTHR);   GLOAD(z2, z4 + j + 2*NTHR);
            GLOAD(x3, l4 + j + 3*NTHR);   GLOAD(z3, z4 + j + 3*NTHR);
            GLOAD(x4, l4 + j + 4*NTHR);   GLOAD(z4_, z4 + j + 4*NTHR);
            GLOAD(x5, l4 + j + 5*NTHR);   GLOAD(z5, z4 + j + 5*NTHR);
            GLOAD(x6, l4 + j + 6*NTHR);   GLOAD(z6, z4 + j + 6*NTHR);
            GLOAD(x7, l4 + j + 7*NTHR);   GLOAD(z7, z4 + j + 7*NTHR);
            GLOAD(x8, l4 + j + 8*NTHR);   GLOAD(z8, z4 + j + 8*NTHR);
            GLOAD(x9, l4 + j + 9*NTHR);   GLOAD(z9, z4 + j + 9*NTHR);
            VMWAIT("18"); score4(x0, z0,  c, (j          ) << 2, av, ai);
            VMWAIT("16"); score4(x1, z1,  c, (j + 1*NTHR) << 2, av, ai);
            VMWAIT("14"); score4(x2, z2,  c, (j + 2*NTHR) << 2, av, ai);
            VMWAIT("12"); score4(x3, z3,  c, (j + 3*NTHR) << 2, av, ai);
            VMWAIT("10"); score4(x4, z4_, c, (j + 4*NTHR) << 2, av, ai);
            VMWAIT("8");  score4(x5, z5,  c, (j + 5*NTHR) << 2, av, ai);
            VMWAIT("6");  score4(x6, z6,  c, (j + 6*NTHR) << 2, av, ai);
            VMWAIT("4");  score4(x7, z7,  c, (j + 7*NTHR) << 2, av, ai);
            VMWAIT("2");  score4(x8, z8,  c, (j + 8*NTHR) << 2, av, ai);
            VMWAIT("0");  score4(x9, z9,  c, (j + 9*NTHR) << 2, av, ai);
        }
        for (; j < j1; j += NTHR) {
            float4 x = l4[j]; float4 z = z4[j];
            score4(x, z, c, j << 2, av, ai);
        }
    }

    // ---- wave (64-lane) reduction ----
    #pragma unroll
    for (int off = 32; off > 0; off >>= 1) {
        float ov = __shfl_down(av, off, 64);
        int   oi = __shfl_down(ai, off, 64);
        amax_combine(av, ai, ov, oi);
    }
    __shared__ float svv[4]; __shared__ int sii[4];
    if (lane == 0) { svv[wid] = av; sii[wid] = ai; }
    __syncthreads();
    if (tid == 0) {
        float bv = svv[0]; int bi = sii[0];
        #pragma unroll
        for (int w = 1; w < 4; ++w) amax_combine(bv, bi, svv[w], sii[w]);
        ws[(size_t)row * SEGS + seg] = make_float2(bv, __int_as_float(bi));
    }
}

__global__ __launch_bounds__(256) void draft_pass2(
    const float2* __restrict__ ws,
    int* __restrict__ out,
    int B)
{
    int r = blockIdx.x * blockDim.x + threadIdx.x;
    if (r >= B) return;
    float v = -INFINITY; int i = 0x7fffffff;
    #pragma unroll
    for (int s = 0; s < SEGS; ++s) {
        float2 p = ws[(size_t)r * SEGS + s];
        amax_combine(v, i, p.x, __float_as_int(p.y));
    }
    out[r] = i;
}

extern "C" void kernel_launch(void* const* d_in, const int* in_sizes, int n_in,
                              void* d_out, int out_size, void* d_ws, size_t ws_size,
                              hipStream_t stream) {
    const float* logits = (const float*)d_in[0];
    const float* temps  = (const float*)d_in[1];
    const float* noise  = (const float*)d_in[2];
    int* out = (int*)d_out;

    const int B = in_sizes[1];              // 256
    const int V = in_sizes[0] / B;          // 128000

    float2* ws = (float2*)d_ws;             // B*SEGS*8 B

    dim3 grid1(SEGS, B);
    draft_pass1<<<grid1, NTHR, 0, stream>>>(logits, temps, noise, ws, V);
    draft_pass2<<<(B + 255) / 256, 256, 0, stream>>>(ws, out, B);
}